// Round 12
// baseline (163.419 us; speedup 1.0000x reference)
//
#include <hip/hip_runtime.h>
#include <hip/hip_bf16.h>

typedef __bf16 bf16;
typedef __attribute__((ext_vector_type(4))) __bf16 bf16x4;
typedef __attribute__((ext_vector_type(8))) __bf16 bf16x8;
typedef __attribute__((ext_vector_type(4))) float f32x4;

#define GLD_LDS16(g, l)                                              \
  __builtin_amdgcn_global_load_lds(                                  \
      (const __attribute__((address_space(1))) void*)(g),            \
      (__attribute__((address_space(3))) void*)(l), 16, 0, 0)

// ---- prep: z<3 -> transpose+cast W[z] (K,N)->(N,K) bf16; z==3 -> cast x ----
__global__ void prep_kernel(const float* __restrict__ x,
                            const float* __restrict__ Wq,
                            const float* __restrict__ Wk,
                            const float* __restrict__ Wv,
                            bf16* __restrict__ xb, bf16* __restrict__ Wt) {
  __shared__ float tile[32][33];
  const int z = blockIdx.z;
  const int t = threadIdx.x;
  if (z < 3) {
    const float* W = (z == 0) ? Wq : ((z == 1) ? Wk : Wv);
    bf16* out = Wt + (size_t)z * 1024 * 1024;
    const int k0 = blockIdx.x * 32, n0 = blockIdx.y * 32;
    const int r = t >> 3, c = (t & 7) * 4;
    float4 v = *reinterpret_cast<const float4*>(&W[(size_t)(k0 + r) * 1024 + n0 + c]);
    tile[r][c + 0] = v.x; tile[r][c + 1] = v.y;
    tile[r][c + 2] = v.z; tile[r][c + 3] = v.w;
    __syncthreads();
    bf16x4 o;
    o[0] = (bf16)tile[c + 0][r]; o[1] = (bf16)tile[c + 1][r];
    o[2] = (bf16)tile[c + 2][r]; o[3] = (bf16)tile[c + 3][r];
    *reinterpret_cast<bf16x4*>(&out[(size_t)(n0 + r) * 1024 + k0 + c]) = o;
  } else {
    const int tid = (blockIdx.y * 32 + blockIdx.x) * 256 + t;
#pragma unroll
    for (int i = 0; i < 8; ++i) {
      const int idx = tid + i * 262144;
      float4 v = reinterpret_cast<const float4*>(x)[idx];
      bf16x4 o;
      o[0] = (bf16)v.x; o[1] = (bf16)v.y; o[2] = (bf16)v.z; o[3] = (bf16)v.w;
      reinterpret_cast<bf16x4*>(xb)[idx] = o;
    }
  }
}

// --------- fused QKV GEMM: C[8192][3072] = x @ Wt^T + bias ----------------
// R7 A-side structure (BM=256 BN=128 BK=64, 8 waves 4Mx2N, 3-deep literal
// LDS ring, XOR swizzle) + NEW: B decoupled from LDS -- B fragments loaded
// one tile ahead, global->register (Wt is L2/L3-resident), double register
// set bE/bO by tile parity. vmcnt(4) boundaries (A-DMA ring only).
__global__ __launch_bounds__(512, 2) void qkv_gemm_kernel(
    const bf16* __restrict__ xb, const bf16* __restrict__ Wt,
    const float* __restrict__ bq, const float* __restrict__ bk,
    const float* __restrict__ bv, bf16* __restrict__ QKV) {
  __shared__ bf16 ldsA[3][256 * 64];  // 96 KB (A only)

  const int n0g = blockIdx.x * 128;
  const int m0 = blockIdx.y * 256;
  const int z = n0g >> 10;
  const float* bias = (z == 0) ? bq : ((z == 1) ? bk : bv);
  const int nloc = n0g & 1023;

  const int t = threadIdx.x;
  const int lane = t & 63, wid = t >> 6;
  const int wr = wid >> 1, wc = wid & 1;
  const int l15 = lane & 15, kg = lane >> 4;

  // A staging: chunk = 64 rows x 64 cols (8 KB), 512 thr x 16 B
  const int trow = t >> 3;
  const int cdst = (t & 7) * 8;
  const int csrc = (((t & 7) * 16) ^ ((trow & 7) << 4)) >> 1;  // pre-swizzled src

  auto stageA = [&](int c, int kt, int buf) {
    GLD_LDS16(xb + (size_t)(m0 + c * 64 + trow) * 1024 + kt + csrc,
              &ldsA[buf][(c * 64 + trow) * 64 + cdst]);
  };
  auto readA = [&](int buf, int mi, int ks) {
    const int row = wr * 64 + mi * 16 + l15;
    const int colb = (ks * 64 + kg * 16) ^ ((l15 & 7) << 4);
    return *reinterpret_cast<const bf16x8*>(&ldsA[buf][row * 64 + (colb >> 1)]);
  };
  // B fragment straight from global (no swizzle): 8 consecutive k per lane
  auto loadB = [&](int ni, int ks, int kt) {
    const int row = wc * 64 + ni * 16 + l15;
    return *reinterpret_cast<const bf16x8*>(
        Wt + (size_t)(n0g + row) * 1024 + kt + ks * 32 + kg * 8);
  };

  f32x4 acc[4][4];
#pragma unroll
  for (int i = 0; i < 4; ++i)
#pragma unroll
    for (int j = 0; j < 4; ++j) { f32x4 zz = {0.f, 0.f, 0.f, 0.f}; acc[i][j] = zz; }

  bf16x8 bE[8], bO[8];  // B register sets, tile-parity alternated

  // prologue (issue order matters for vmcnt): A(0) x4, B(0) x8, A(1) x4
#pragma unroll
  for (int c = 0; c < 4; ++c) stageA(c, 0, 0);
  __builtin_amdgcn_sched_barrier(0);
#pragma unroll
  for (int ni = 0; ni < 4; ++ni) {
    bE[ni * 2]     = loadB(ni, 0, 0);
    bE[ni * 2 + 1] = loadB(ni, 1, 0);
  }
  __builtin_amdgcn_sched_barrier(0);
#pragma unroll
  for (int c = 0; c < 4; ++c) stageA(c, 64, 1);

// One K-tile. Boundary: vmcnt(4) = {A(t),B(t) done; A(t+1) in flight}.
// Body: load B(t+1)->BNX; ds_read A(t); SB(0); stage A(t+2); 32 MFMA w/ BC.
#define KTILE(RB, WB, kt, DO_STAGE, LAST, BC, BNX)                             \
  {                                                                            \
    if (LAST) { asm volatile("s_waitcnt vmcnt(0)" ::: "memory"); }             \
    else      { asm volatile("s_waitcnt vmcnt(4)" ::: "memory"); }             \
    __builtin_amdgcn_s_barrier();                                              \
    if (!(LAST)) {                                                             \
      _Pragma("unroll")                                                        \
      for (int ni = 0; ni < 4; ++ni) {                                         \
        BNX[ni * 2]     = loadB(ni, 0, (kt) + 64);                             \
        BNX[ni * 2 + 1] = loadB(ni, 1, (kt) + 64);                             \
      }                                                                        \
    }                                                                          \
    bf16x8 af[4][2];                                                           \
    _Pragma("unroll")                                                          \
    for (int mi = 0; mi < 4; ++mi)                                             \
      _Pragma("unroll")                                                        \
      for (int ks = 0; ks < 2; ++ks) af[mi][ks] = readA(RB, mi, ks);           \
    __builtin_amdgcn_sched_barrier(0);                                         \
    if (DO_STAGE) {                                                            \
      stageA(0, (kt) + 128, WB); stageA(1, (kt) + 128, WB);                    \
      stageA(2, (kt) + 128, WB); stageA(3, (kt) + 128, WB);                    \
    }                                                                          \
    __builtin_amdgcn_s_setprio(1);                                             \
    _Pragma("unroll")                                                          \
    for (int mi = 0; mi < 4; ++mi)                                             \
      _Pragma("unroll")                                                        \
      for (int ni = 0; ni < 4; ++ni) {                                         \
        acc[mi][ni] = __builtin_amdgcn_mfma_f32_16x16x32_bf16(                 \
            af[mi][0], BC[ni * 2], acc[mi][ni], 0, 0, 0);                      \
        acc[mi][ni] = __builtin_amdgcn_mfma_f32_16x16x32_bf16(                 \
            af[mi][1], BC[ni * 2 + 1], acc[mi][ni], 0, 0, 0);                  \
      }                                                                        \
    __builtin_amdgcn_s_setprio(0);                                             \
  }

  // tiles 0..11: ring x parity has period 6 -> two unrolled groups of 6
  for (int g = 0; g < 2; ++g) {
    const int kb = g * 384;
    KTILE(0, 2, kb,       true, false, bE, bO);
    KTILE(1, 0, kb + 64,  true, false, bO, bE);
    KTILE(2, 1, kb + 128, true, false, bE, bO);
    KTILE(0, 2, kb + 192, true, false, bO, bE);
    KTILE(1, 0, kb + 256, true, false, bE, bO);
    KTILE(2, 1, kb + 320, true, false, bO, bE);
  }
  // tail: tiles 12..15
  KTILE(0, 2, 768, true,  false, bE, bO);  // stages A(14)
  KTILE(1, 0, 832, true,  false, bO, bE);  // stages A(15), loads B(14)
  KTILE(2, 1, 896, false, false, bE, bO);  // loads B(15)
  KTILE(0, 2, 960, false, true,  bO, bE);
#undef KTILE

  // epilogue: C/D layout col = lane&15, row = (lane>>4)*4 + reg  [m89/m91]
  const int rowb = kg * 4;
#pragma unroll
  for (int ni = 0; ni < 4; ++ni) {
    const int cl = wc * 64 + ni * 16 + l15;
    const float bv_ = bias[nloc + cl];
#pragma unroll
    for (int mi = 0; mi < 4; ++mi) {
      const int row = m0 + wr * 64 + mi * 16 + rowb;
#pragma unroll
      for (int j = 0; j < 4; ++j)
        QKV[(size_t)(row + j) * 3072 + n0g + cl] = (bf16)(acc[mi][ni][j] + bv_);
    }
  }
}

// ------- local attention, window +-2; 2 positions per wave ----------------
__global__ void local_attn_kernel(const bf16* __restrict__ QKV,
                                  float* __restrict__ out) {
  const int t = threadIdx.x;
  const int lane = t & 63, wid = t >> 6;
  const int p0 = blockIdx.x * 8 + wid * 2;  // even; block = 8 consecutive pos
  const int s0 = p0 & 2047;
  const size_t hoff = (size_t)lane * 16;

  float q0f[16], q1f[16];
  {
    const bf16* qp = QKV + (size_t)p0 * 3072 + hoff;
    bf16x8 a0 = *reinterpret_cast<const bf16x8*>(qp);
    bf16x8 a1 = *reinterpret_cast<const bf16x8*>(qp + 8);
    bf16x8 b0 = *reinterpret_cast<const bf16x8*>(qp + 3072);
    bf16x8 b1 = *reinterpret_cast<const bf16x8*>(qp + 3072 + 8);
#pragma unroll
    for (int j = 0; j < 8; ++j) {
      q0f[j] = (float)a0[j]; q0f[8 + j] = (float)a1[j];
      q1f[j] = (float)b0[j]; q1f[8 + j] = (float)b1[j];
    }
  }

  bf16x8 kr[6][2], vr[6][2];
  bool val[6];
#pragma unroll
  for (int r = 0; r < 6; ++r) {
    const int sr = s0 - 2 + r;
    val[r] = (sr >= 0) && (sr < 2048);
    if (val[r]) {
      const bf16* kp = QKV + (size_t)(p0 - 2 + r) * 3072 + 1024 + hoff;
      kr[r][0] = *reinterpret_cast<const bf16x8*>(kp);
      kr[r][1] = *reinterpret_cast<const bf16x8*>(kp + 8);
      vr[r][0] = *reinterpret_cast<const bf16x8*>(kp + 1024);
      vr[r][1] = *reinterpret_cast<const bf16x8*>(kp + 1024 + 8);
    } else {
      bf16x8 zz;
#pragma unroll
      for (int j = 0; j < 8; ++j) zz[j] = (bf16)0.f;
      kr[r][0] = zz; kr[r][1] = zz; vr[r][0] = zz; vr[r][1] = zz;
    }
  }

  float d0[5], d1[5];
#pragma unroll
  for (int w = 0; w < 5; ++w) {
    float a = 0.f, b = 0.f;
#pragma unroll
    for (int j = 0; j < 8; ++j) {
      a += q0f[j] * (float)kr[w][0][j] + q0f[8 + j] * (float)kr[w][1][j];
      b += q1f[j] * (float)kr[w + 1][0][j] + q1f[8 + j] * (float)kr[w + 1][1][j];
    }
    d0[w] = a; d1[w] = b;
  }
#pragma unroll
  for (int off = 32; off >= 1; off >>= 1) {
#pragma unroll
    for (int w = 0; w < 5; ++w) {
      d0[w] += __shfl_xor(d0[w], off, 64);
      d1[w] += __shfl_xor(d1[w], off, 64);
    }
  }

  const float NEG = -__builtin_inff();
  float sc0[5], sc1[5];
#pragma unroll
  for (int w = 0; w < 5; ++w) {
    sc0[w] = val[w] ? d0[w] * (1.0f / 32.0f) : NEG;
    sc1[w] = val[w + 1] ? d1[w] * (1.0f / 32.0f) : NEG;
  }
  float m0_ = NEG, m1_ = NEG;
#pragma unroll
  for (int w = 0; w < 5; ++w) { m0_ = fmaxf(m0_, sc0[w]); m1_ = fmaxf(m1_, sc1[w]); }
  float e0[5], e1[5], su0 = 0.f, su1 = 0.f;
#pragma unroll
  for (int w = 0; w < 5; ++w) {
    e0[w] = __expf(sc0[w] - m0_); su0 += e0[w];
    e1[w] = __expf(sc1[w] - m1_); su1 += e1[w];
  }
  const float i0 = 1.0f / su0, i1 = 1.0f / su1;

  float of0[16], of1[16];
#pragma unroll
  for (int j = 0; j < 16; ++j) { of0[j] = 0.f; of1[j] = 0.f; }
#pragma unroll
  for (int w = 0; w < 5; ++w) {
    const float p0w = e0[w] * i0;
    const float p1w = e1[w] * i1;
#pragma unroll
    for (int j = 0; j < 8; ++j) {
      of0[j]     += p0w * (float)vr[w][0][j];
      of0[8 + j] += p0w * (float)vr[w][1][j];
      of1[j]     += p1w * (float)vr[w + 1][0][j];
      of1[8 + j] += p1w * (float)vr[w + 1][1][j];
    }
  }

  float* op0 = out + (size_t)p0 * 1024 + hoff;
  float* op1 = op0 + 1024;
#pragma unroll
  for (int j4 = 0; j4 < 4; ++j4) {
    f32x4 o0 = {of0[4 * j4], of0[4 * j4 + 1], of0[4 * j4 + 2], of0[4 * j4 + 3]};
    f32x4 o1 = {of1[4 * j4], of1[4 * j4 + 1], of1[4 * j4 + 2], of1[4 * j4 + 3]};
    *reinterpret_cast<f32x4*>(op0 + 4 * j4) = o0;
    *reinterpret_cast<f32x4*>(op1 + 4 * j4) = o1;
  }
}

extern "C" void kernel_launch(void* const* d_in, const int* in_sizes, int n_in,
                              void* d_out, int out_size, void* d_ws,
                              size_t ws_size, hipStream_t stream) {
  const float* x  = (const float*)d_in[0];
  const float* Wq = (const float*)d_in[1];
  const float* bq = (const float*)d_in[2];
  const float* Wk = (const float*)d_in[3];
  const float* bk = (const float*)d_in[4];
  const float* Wv = (const float*)d_in[5];
  const float* bv = (const float*)d_in[6];

  char* ws = (char*)d_ws;
  bf16* xb  = (bf16*)ws;                       // 16 MB: x as bf16
  bf16* Wt  = (bf16*)(ws + (size_t)16777216);  // 6 MB: [3072][1024] W^T bf16
  bf16* QKV = (bf16*)(ws + (size_t)23068672);  // 48 MB: fused [8192][3072]
  float* outf = (float*)d_out;

  prep_kernel<<<dim3(32, 32, 4), 256, 0, stream>>>(x, Wq, Wk, Wv, xb, Wt);
  qkv_gemm_kernel<<<dim3(24, 32), 512, 0, stream>>>(xb, Wt, bq, bk, bv, QKV);
  local_attn_kernel<<<1024, 256, 0, stream>>>(QKV, outf);
}

// Round 14
// 98.150 us; speedup vs baseline: 1.6650x; 1.6650x over previous
//
#include <hip/hip_runtime.h>
#include <hip/hip_bf16.h>

typedef __bf16 bf16;
typedef __attribute__((ext_vector_type(4))) __bf16 bf16x4;
typedef __attribute__((ext_vector_type(8))) __bf16 bf16x8;
typedef __attribute__((ext_vector_type(4))) float f32x4;

#define GLD_LDS16(g, l)                                              \
  __builtin_amdgcn_global_load_lds(                                  \
      (const __attribute__((address_space(1))) void*)(g),            \
      (__attribute__((address_space(3))) void*)(l), 16, 0, 0)

// ---- prep: z<3 -> transpose+cast W[z] (K,N)->(N,K) bf16; z==3 -> cast x ----
__global__ void prep_kernel(const float* __restrict__ x,
                            const float* __restrict__ Wq,
                            const float* __restrict__ Wk,
                            const float* __restrict__ Wv,
                            bf16* __restrict__ xb, bf16* __restrict__ Wt) {
  __shared__ float tile[32][33];
  const int z = blockIdx.z;
  const int t = threadIdx.x;
  if (z < 3) {
    const float* W = (z == 0) ? Wq : ((z == 1) ? Wk : Wv);
    bf16* out = Wt + (size_t)z * 1024 * 1024;
    const int k0 = blockIdx.x * 32, n0 = blockIdx.y * 32;
    const int r = t >> 3, c = (t & 7) * 4;
    float4 v = *reinterpret_cast<const float4*>(&W[(size_t)(k0 + r) * 1024 + n0 + c]);
    tile[r][c + 0] = v.x; tile[r][c + 1] = v.y;
    tile[r][c + 2] = v.z; tile[r][c + 3] = v.w;
    __syncthreads();
    bf16x4 o;
    o[0] = (bf16)tile[c + 0][r]; o[1] = (bf16)tile[c + 1][r];
    o[2] = (bf16)tile[c + 2][r]; o[3] = (bf16)tile[c + 3][r];
    *reinterpret_cast<bf16x4*>(&out[(size_t)(n0 + r) * 1024 + k0 + c]) = o;
  } else {
    const int tid = (blockIdx.y * 32 + blockIdx.x) * 256 + t;
#pragma unroll
    for (int i = 0; i < 8; ++i) {
      const int idx = tid + i * 262144;
      float4 v = reinterpret_cast<const float4*>(x)[idx];
      bf16x4 o;
      o[0] = (bf16)v.x; o[1] = (bf16)v.y; o[2] = (bf16)v.z; o[3] = (bf16)v.w;
      reinterpret_cast<bf16x4*>(xb)[idx] = o;
    }
  }
}

// --------- fused QKV GEMM: C[8192][3072] = x @ Wt^T + bias ----------------
// 8-phase 256x256 template (T2+T3+T4+T5): BK=64, 8 waves (2M x 4N), per-wave
// 128x64, acc[ah][bh][4][2]. LDS 2 bufs x (A 2 halves + B 2 halves) = 128 KB.
// Phase order per K-tile: (A0B0)(A0B1)(A1B1)(A1B0); stage stream A0,B0,B1,A1
// one half (2 gload_lds) per phase, 4-phase lead; counted vmcnt(4) at
// P0/P1/P2, none at P3 (ledger-derived; tail 4/2/0). Literal buffer indices.
__global__ __launch_bounds__(512, 2) void qkv_gemm_kernel(
    const bf16* __restrict__ xb, const bf16* __restrict__ Wt,
    const float* __restrict__ bq, const float* __restrict__ bk,
    const float* __restrict__ bv, bf16* __restrict__ QKV) {
  __shared__ bf16 ldsA[2][256 * 64];  // 64 KB: [buf][half*8192 + row*64 + col]
  __shared__ bf16 ldsB[2][256 * 64];  // 64 KB

  const int n0g = blockIdx.x * 256;
  const int m0 = blockIdx.y * 256;
  const int z = n0g >> 10;  // 256-tiles never cross q/k/v boundaries
  const float* bias = (z == 0) ? bq : ((z == 1) ? bk : bv);
  const int nloc = n0g & 1023;

  const int t = threadIdx.x;
  const int lane = t & 63, wid = t >> 6;
  const int wm = wid >> 2, wn = wid & 3;  // per-phase quadrant sub-tile 64x32
  const int l15 = lane & 15, kg = lane >> 4;

  // staging: chunk = 64 rows x 64 cols (8 KB), 512 thr x 16 B (R7-proven)
  const int trow = t >> 3;
  const int csrc = (((t & 7) * 16) ^ ((trow & 7) << 4)) >> 1;  // pre-swizzled

  auto stA = [&](int h, int c, int kt, int wb) {
    GLD_LDS16(xb + (size_t)(m0 + h * 128 + c * 64 + trow) * 1024 + kt + csrc,
              &ldsA[wb][h * 8192 + c * 4096 + t * 8]);
  };
  auto stB = [&](int h, int c, int kt, int wb) {
    GLD_LDS16(Wt + (size_t)(n0g + h * 128 + c * 64 + trow) * 1024 + kt + csrc,
              &ldsB[wb][h * 8192 + c * 4096 + t * 8]);
  };
#define STAGE_A(H, KT, WB) { stA(H, 0, KT, WB); stA(H, 1, KT, WB); }
#define STAGE_B(H, KT, WB) { stB(H, 0, KT, WB); stB(H, 1, KT, WB); }

  // swizzled fragment reads (64-elem rows, identical transform to staging)
  auto readA = [&](int rb, int ah, int mi, int ks) {
    const int row = wm * 64 + mi * 16 + l15;  // 0..127 within half
    const int colb = (ks * 64 + kg * 16) ^ ((l15 & 7) << 4);
    return *reinterpret_cast<const bf16x8*>(
        &ldsA[rb][ah * 8192 + row * 64 + (colb >> 1)]);
  };
  auto readB = [&](int rb, int bh, int ni, int ks) {
    const int row = wn * 32 + ni * 16 + l15;  // 0..127 within half
    const int colb = (ks * 64 + kg * 16) ^ ((l15 & 7) << 4);
    return *reinterpret_cast<const bf16x8*>(
        &ldsB[rb][bh * 8192 + row * 64 + (colb >> 1)]);
  };

  f32x4 acc[2][2][4][2];
#pragma unroll
  for (int a = 0; a < 2; ++a)
#pragma unroll
    for (int b = 0; b < 2; ++b)
#pragma unroll
      for (int i = 0; i < 4; ++i)
#pragma unroll
        for (int j = 0; j < 2; ++j) {
          f32x4 zz = {0.f, 0.f, 0.f, 0.f};
          acc[a][b][i][j] = zz;
        }

  bf16x8 af[4][2], bf0[2][2], bf1[2][2];

#define MFMA16(AH, BH, BF)                                                     \
    _Pragma("unroll")                                                          \
    for (int mi = 0; mi < 4; ++mi)                                             \
      _Pragma("unroll")                                                        \
      for (int ni = 0; ni < 2; ++ni) {                                         \
        acc[AH][BH][mi][ni] = __builtin_amdgcn_mfma_f32_16x16x32_bf16(         \
            af[mi][0], BF[ni][0], acc[AH][BH][mi][ni], 0, 0, 0);               \
        acc[AH][BH][mi][ni] = __builtin_amdgcn_mfma_f32_16x16x32_bf16(         \
            af[mi][1], BF[ni][1], acc[AH][BH][mi][ni], 0, 0, 0);               \
      }

// P0: quadrant (A0,B0). 12 ds_reads; stage next tile's A0; vmcnt(WN).
#define PHASE0(RB, WB, KST, DO_STAGE, WN)                                      \
  {                                                                            \
    asm volatile("s_waitcnt vmcnt(" #WN ")" ::: "memory");                     \
    __builtin_amdgcn_s_barrier();                                              \
    __builtin_amdgcn_sched_barrier(0);                                         \
    _Pragma("unroll")                                                          \
    for (int mi = 0; mi < 4; ++mi)                                             \
      _Pragma("unroll")                                                        \
      for (int ks = 0; ks < 2; ++ks) af[mi][ks] = readA(RB, 0, mi, ks);        \
    _Pragma("unroll")                                                          \
    for (int ni = 0; ni < 2; ++ni)                                             \
      _Pragma("unroll")                                                        \
      for (int ks = 0; ks < 2; ++ks) bf0[ni][ks] = readB(RB, 0, ni, ks);       \
    __builtin_amdgcn_sched_barrier(0);                                         \
    if (DO_STAGE) STAGE_A(0, KST, WB);                                         \
    asm volatile("s_waitcnt lgkmcnt(0)" ::: "memory");                         \
    __builtin_amdgcn_sched_barrier(0);                                         \
    __builtin_amdgcn_s_setprio(1);                                             \
    MFMA16(0, 0, bf0)                                                          \
    __builtin_amdgcn_s_setprio(0);                                             \
  }

// P1: quadrant (A0,B1). af reused; read bf1; stage B0.
#define PHASE1(RB, WB, KST, DO_STAGE, WN)                                      \
  {                                                                            \
    asm volatile("s_waitcnt vmcnt(" #WN ")" ::: "memory");                     \
    __builtin_amdgcn_s_barrier();                                              \
    __builtin_amdgcn_sched_barrier(0);                                         \
    _Pragma("unroll")                                                          \
    for (int ni = 0; ni < 2; ++ni)                                             \
      _Pragma("unroll")                                                        \
      for (int ks = 0; ks < 2; ++ks) bf1[ni][ks] = readB(RB, 1, ni, ks);       \
    __builtin_amdgcn_sched_barrier(0);                                         \
    if (DO_STAGE) STAGE_B(0, KST, WB);                                         \
    asm volatile("s_waitcnt lgkmcnt(0)" ::: "memory");                         \
    __builtin_amdgcn_sched_barrier(0);                                         \
    __builtin_amdgcn_s_setprio(1);                                             \
    MFMA16(0, 1, bf1)                                                          \
    __builtin_amdgcn_s_setprio(0);                                             \
  }

// P2: quadrant (A1,B1). re-read af (half 1); bf1 reused; stage B1.
#define PHASE2(RB, WB, KST, DO_STAGE, WN)                                      \
  {                                                                            \
    asm volatile("s_waitcnt vmcnt(" #WN ")" ::: "memory");                     \
    __builtin_amdgcn_s_barrier();                                              \
    __builtin_amdgcn_sched_barrier(0);                                         \
    _Pragma("unroll")                                                          \
    for (int mi = 0; mi < 4; ++mi)                                             \
      _Pragma("unroll")                                                        \
      for (int ks = 0; ks < 2; ++ks) af[mi][ks] = readA(RB, 1, mi, ks);        \
    __builtin_amdgcn_sched_barrier(0);                                         \
    if (DO_STAGE) STAGE_B(1, KST, WB);                                         \
    asm volatile("s_waitcnt lgkmcnt(0)" ::: "memory");                         \
    __builtin_amdgcn_sched_barrier(0);                                         \
    __builtin_amdgcn_s_setprio(1);                                             \
    MFMA16(1, 1, bf1)                                                          \
    __builtin_amdgcn_s_setprio(0);                                             \
  }

// P3: quadrant (A1,B0). all registers live; no reads, no wait, no barrier;
// stage A1. bf0 read at P0, af at P2 (both lgkm'd already).
#define PHASE3(RB, WB, KST, DO_STAGE)                                          \
  {                                                                            \
    if (DO_STAGE) STAGE_A(1, KST, WB);                                         \
    __builtin_amdgcn_s_setprio(1);                                             \
    MFMA16(1, 0, bf0)                                                          \
    __builtin_amdgcn_s_setprio(0);                                             \
  }

#define KTILE(RB, WB, KST, DO_STAGE)                                           \
  PHASE0(RB, WB, KST, DO_STAGE, 4)                                             \
  PHASE1(RB, WB, KST, DO_STAGE, 4)                                             \
  PHASE2(RB, WB, KST, DO_STAGE, 4)                                             \
  PHASE3(RB, WB, KST, DO_STAGE)

  // prologue: stage tile 0's halves in stream order (8 loads outstanding)
  STAGE_A(0, 0, 0) STAGE_B(0, 0, 0) STAGE_B(1, 0, 0) STAGE_A(1, 0, 0)

  // tiles 0..13 (pairs keep buffer indices literal); KST = (t+1)*64
  for (int tp = 0; tp < 7; ++tp) {
    const int kb = tp * 128;
    KTILE(0, 1, kb + 64, 1)
    KTILE(1, 0, kb + 128, 1)
  }
  // tile 14: stages tile 15 into buf 1
  KTILE(0, 1, 960, 1)
  // tile 15: tail — no staging; waits 4/2/0/none
  PHASE0(1, 0, 0, 0, 4)
  PHASE1(1, 0, 0, 0, 2)
  PHASE2(1, 0, 0, 0, 0)
  PHASE3(1, 0, 0, 0)
#undef KTILE
#undef PHASE0
#undef PHASE1
#undef PHASE2
#undef PHASE3
#undef MFMA16
#undef STAGE_A
#undef STAGE_B

  // epilogue: C/D layout col = lane&15, row = (lane>>4)*4 + reg  [m89/m91]
  const int rowb = kg * 4;
#pragma unroll
  for (int ah = 0; ah < 2; ++ah)
#pragma unroll
    for (int bh = 0; bh < 2; ++bh)
#pragma unroll
      for (int ni = 0; ni < 2; ++ni) {
        const int cl = bh * 128 + wn * 32 + ni * 16 + l15;
        const float bv_ = bias[nloc + cl];
#pragma unroll
        for (int mi = 0; mi < 4; ++mi) {
          const int row = m0 + ah * 128 + wm * 64 + mi * 16 + rowb;
#pragma unroll
          for (int j = 0; j < 4; ++j)
            QKV[(size_t)(row + j) * 3072 + n0g + cl] =
                (bf16)(acc[ah][bh][mi][ni][j] + bv_);
        }
      }
}

// ------- local attention, window +-2; 2 positions per wave ----------------
__global__ void local_attn_kernel(const bf16* __restrict__ QKV,
                                  float* __restrict__ out) {
  const int t = threadIdx.x;
  const int lane = t & 63, wid = t >> 6;
  const int p0 = blockIdx.x * 8 + wid * 2;  // even
  const int s0 = p0 & 2047;
  const size_t hoff = (size_t)lane * 16;

  float q0f[16], q1f[16];
  {
    const bf16* qp = QKV + (size_t)p0 * 3072 + hoff;
    bf16x8 a0 = *reinterpret_cast<const bf16x8*>(qp);
    bf16x8 a1 = *reinterpret_cast<const bf16x8*>(qp + 8);
    bf16x8 b0 = *reinterpret_cast<const bf16x8*>(qp + 3072);
    bf16x8 b1 = *reinterpret_cast<const bf16x8*>(qp + 3072 + 8);
#pragma unroll
    for (int j = 0; j < 8; ++j) {
      q0f[j] = (float)a0[j]; q0f[8 + j] = (float)a1[j];
      q1f[j] = (float)b0[j]; q1f[8 + j] = (float)b1[j];
    }
  }

  bf16x8 kr[6][2], vr[6][2];
  bool val[6];
#pragma unroll
  for (int r = 0; r < 6; ++r) {
    const int sr = s0 - 2 + r;
    val[r] = (sr >= 0) && (sr < 2048);
    if (val[r]) {
      const bf16* kp = QKV + (size_t)(p0 - 2 + r) * 3072 + 1024 + hoff;
      kr[r][0] = *reinterpret_cast<const bf16x8*>(kp);
      kr[r][1] = *reinterpret_cast<const bf16x8*>(kp + 8);
      vr[r][0] = *reinterpret_cast<const bf16x8*>(kp + 1024);
      vr[r][1] = *reinterpret_cast<const bf16x8*>(kp + 1024 + 8);
    } else {
      bf16x8 zz;
#pragma unroll
      for (int j = 0; j < 8; ++j) zz[j] = (bf16)0.f;
      kr[r][0] = zz; kr[r][1] = zz; vr[r][0] = zz; vr[r][1] = zz;
    }
  }

  float d0[5], d1[5];
#pragma unroll
  for (int w = 0; w < 5; ++w) {
    float a = 0.f, b = 0.f;
#pragma unroll
    for (int j = 0; j < 8; ++j) {
      a += q0f[j] * (float)kr[w][0][j] + q0f[8 + j] * (float)kr[w][1][j];
      b += q1f[j] * (float)kr[w + 1][0][j] + q1f[8 + j] * (float)kr[w + 1][1][j];
    }
    d0[w] = a; d1[w] = b;
  }
#pragma unroll
  for (int off = 32; off >= 1; off >>= 1) {
#pragma unroll
    for (int w = 0; w < 5; ++w) {
      d0[w] += __shfl_xor(d0[w], off, 64);
      d1[w] += __shfl_xor(d1[w], off, 64);
    }
  }

  const float NEG = -__builtin_inff();
  float sc0[5], sc1[5];
#pragma unroll
  for (int w = 0; w < 5; ++w) {
    sc0[w] = val[w] ? d0[w] * (1.0f / 32.0f) : NEG;
    sc1[w] = val[w + 1] ? d1[w] * (1.0f / 32.0f) : NEG;
  }
  float m0_ = NEG, m1_ = NEG;
#pragma unroll
  for (int w = 0; w < 5; ++w) { m0_ = fmaxf(m0_, sc0[w]); m1_ = fmaxf(m1_, sc1[w]); }
  float e0[5], e1[5], su0 = 0.f, su1 = 0.f;
#pragma unroll
  for (int w = 0; w < 5; ++w) {
    e0[w] = __expf(sc0[w] - m0_); su0 += e0[w];
    e1[w] = __expf(sc1[w] - m1_); su1 += e1[w];
  }
  const float i0 = 1.0f / su0, i1 = 1.0f / su1;

  float of0[16], of1[16];
#pragma unroll
  for (int j = 0; j < 16; ++j) { of0[j] = 0.f; of1[j] = 0.f; }
#pragma unroll
  for (int w = 0; w < 5; ++w) {
    const float p0w = e0[w] * i0;
    const float p1w = e1[w] * i1;
#pragma unroll
    for (int j = 0; j < 8; ++j) {
      of0[j]     += p0w * (float)vr[w][0][j];
      of0[8 + j] += p0w * (float)vr[w][1][j];
      of1[j]     += p1w * (float)vr[w + 1][0][j];
      of1[8 + j] += p1w * (float)vr[w + 1][1][j];
    }
  }

  float* op0 = out + (size_t)p0 * 1024 + hoff;
  float* op1 = op0 + 1024;
#pragma unroll
  for (int j4 = 0; j4 < 4; ++j4) {
    f32x4 o0 = {of0[4 * j4], of0[4 * j4 + 1], of0[4 * j4 + 2], of0[4 * j4 + 3]};
    f32x4 o1 = {of1[4 * j4], of1[4 * j4 + 1], of1[4 * j4 + 2], of1[4 * j4 + 3]};
    *reinterpret_cast<f32x4*>(op0 + 4 * j4) = o0;
    *reinterpret_cast<f32x4*>(op1 + 4 * j4) = o1;
  }
}

extern "C" void kernel_launch(void* const* d_in, const int* in_sizes, int n_in,
                              void* d_out, int out_size, void* d_ws,
                              size_t ws_size, hipStream_t stream) {
  const float* x  = (const float*)d_in[0];
  const float* Wq = (const float*)d_in[1];
  const float* bq = (const float*)d_in[2];
  const float* Wk = (const float*)d_in[3];
  const float* bk = (const float*)d_in[4];
  const float* Wv = (const float*)d_in[5];
  const float* bv = (const float*)d_in[6];

  char* ws = (char*)d_ws;
  bf16* xb  = (bf16*)ws;                       // 16 MB: x as bf16
  bf16* Wt  = (bf16*)(ws + (size_t)16777216);  // 6 MB: [3072][1024] W^T bf16
  bf16* QKV = (bf16*)(ws + (size_t)23068672);  // 48 MB: fused [8192][3072]
  float* outf = (float*)d_out;

  prep_kernel<<<dim3(32, 32, 4), 256, 0, stream>>>(x, Wq, Wk, Wv, xb, Wt);
  qkv_gemm_kernel<<<dim3(12, 32), 512, 0, stream>>>(xb, Wt, bq, bk, bv, QKV);
  local_attn_kernel<<<1024, 256, 0, stream>>>(QKV, outf);
}

// Round 15
// 98.020 us; speedup vs baseline: 1.6672x; 1.0013x over previous
//
#include <hip/hip_runtime.h>
#include <hip/hip_bf16.h>

typedef __bf16 bf16;
typedef __attribute__((ext_vector_type(4))) __bf16 bf16x4;
typedef __attribute__((ext_vector_type(8))) __bf16 bf16x8;
typedef __attribute__((ext_vector_type(4))) float f32x4;

#define GLD_LDS16(g, l)                                              \
  __builtin_amdgcn_global_load_lds(                                  \
      (const __attribute__((address_space(1))) void*)(g),            \
      (__attribute__((address_space(3))) void*)(l), 16, 0, 0)

// ---- prep: z<3 -> transpose+cast W[z] (K,N)->(N,K) bf16; z==3 -> cast x ----
__global__ void prep_kernel(const float* __restrict__ x,
                            const float* __restrict__ Wq,
                            const float* __restrict__ Wk,
                            const float* __restrict__ Wv,
                            bf16* __restrict__ xb, bf16* __restrict__ Wt) {
  __shared__ float tile[32][33];
  const int z = blockIdx.z;
  const int t = threadIdx.x;
  if (z < 3) {
    const float* W = (z == 0) ? Wq : ((z == 1) ? Wk : Wv);
    bf16* out = Wt + (size_t)z * 1024 * 1024;
    const int k0 = blockIdx.x * 32, n0 = blockIdx.y * 32;
    const int r = t >> 3, c = (t & 7) * 4;
    float4 v = *reinterpret_cast<const float4*>(&W[(size_t)(k0 + r) * 1024 + n0 + c]);
    tile[r][c + 0] = v.x; tile[r][c + 1] = v.y;
    tile[r][c + 2] = v.z; tile[r][c + 3] = v.w;
    __syncthreads();
    bf16x4 o;
    o[0] = (bf16)tile[c + 0][r]; o[1] = (bf16)tile[c + 1][r];
    o[2] = (bf16)tile[c + 2][r]; o[3] = (bf16)tile[c + 3][r];
    *reinterpret_cast<bf16x4*>(&out[(size_t)(n0 + r) * 1024 + k0 + c]) = o;
  } else {
    const int tid = (blockIdx.y * 32 + blockIdx.x) * 256 + t;
#pragma unroll
    for (int i = 0; i < 8; ++i) {
      const int idx = tid + i * 262144;
      float4 v = reinterpret_cast<const float4*>(x)[idx];
      bf16x4 o;
      o[0] = (bf16)v.x; o[1] = (bf16)v.y; o[2] = (bf16)v.z; o[3] = (bf16)v.w;
      reinterpret_cast<bf16x4*>(xb)[idx] = o;
    }
  }
}

// --------- fused QKV GEMM: C[8192][3072] = x @ Wt^T + bias ----------------
// 8-phase template, BM=256 BN=192 BK=64, grid 32x16 = 512 = EXACTLY 2 rounds
// (R14's 384 = 1.5 rounds wasted 25% of the machine; per-CU rate was +31%).
// 8 waves 4Mx2N; quadrant (Ah 128 x Bh 96); 12 MFMA/phase; acc[2][2][2][3].
// LDS 2 bufs x (A 32K + B 24K) = 112 KB. B-half = 2 overlapping 64-row DMA
// chunks (rows 0-63, 32-95; 32-63 double-written identically) so DMA count
// stays 2/half and the R14 vmcnt ledger is unchanged: vmcnt(4) @P0/P1/P2,
// none @P3; tail 4/2/0. Literal buffer indices.
__global__ __launch_bounds__(512, 2) void qkv_gemm_kernel(
    const bf16* __restrict__ xb, const bf16* __restrict__ Wt,
    const float* __restrict__ bq, const float* __restrict__ bk,
    const float* __restrict__ bv, bf16* __restrict__ QKV) {
  __shared__ bf16 ldsA[2][256 * 64];  // 64 KB: [buf][half*8192 + row*64 + col]
  __shared__ bf16 ldsB[2][192 * 64];  // 48 KB: [buf][half*6144 + row*64 + col]

  const int n0g = blockIdx.x * 192;  // may cross q/k/v boundaries
  const int m0 = blockIdx.y * 256;

  const int t = threadIdx.x;
  const int lane = t & 63, wid = t >> 6;
  const int wm = wid >> 1, wn = wid & 1;  // 4M x 2N waves
  const int l15 = lane & 15, kg = lane >> 4;

  // staging: chunk = 64 rows x 64 cols (8 KB), 512 thr x 16 B (R7-proven)
  const int trow = t >> 3;
  const int csrc = (((t & 7) * 16) ^ ((trow & 7) << 4)) >> 1;  // pre-swizzled

  auto stA = [&](int h, int c, int kt, int wb) {
    GLD_LDS16(xb + (size_t)(m0 + h * 128 + c * 64 + trow) * 1024 + kt + csrc,
              &ldsA[wb][h * 8192 + c * 4096 + t * 8]);
  };
  // B half h: chunk 0 = rows 0..63, chunk 1 = rows 32..95 (overlap benign)
  auto stB = [&](int h, int c, int kt, int wb) {
    GLD_LDS16(Wt + (size_t)(n0g + h * 96 + c * 32 + trow) * 1024 + kt + csrc,
              &ldsB[wb][h * 6144 + c * 2048 + t * 8]);
  };
#define STAGE_A(H, KT, WB) { stA(H, 0, KT, WB); stA(H, 1, KT, WB); }
#define STAGE_B(H, KT, WB) { stB(H, 0, KT, WB); stB(H, 1, KT, WB); }

  // swizzled fragment reads (64-elem rows, same transform as staging)
  auto readA = [&](int rb, int ah, int mi, int ks) {
    const int row = wm * 32 + mi * 16 + l15;  // 0..127 within half
    const int colb = (ks * 64 + kg * 16) ^ ((l15 & 7) << 4);
    return *reinterpret_cast<const bf16x8*>(
        &ldsA[rb][ah * 8192 + row * 64 + (colb >> 1)]);
  };
  auto readB = [&](int rb, int bh, int ni, int ks) {
    const int row = wn * 48 + ni * 16 + l15;  // 0..95 within half
    const int colb = (ks * 64 + kg * 16) ^ ((l15 & 7) << 4);
    return *reinterpret_cast<const bf16x8*>(
        &ldsB[rb][bh * 6144 + row * 64 + (colb >> 1)]);
  };

  f32x4 acc[2][2][2][3];
#pragma unroll
  for (int a = 0; a < 2; ++a)
#pragma unroll
    for (int b = 0; b < 2; ++b)
#pragma unroll
      for (int i = 0; i < 2; ++i)
#pragma unroll
        for (int j = 0; j < 3; ++j) {
          f32x4 zz = {0.f, 0.f, 0.f, 0.f};
          acc[a][b][i][j] = zz;
        }

  bf16x8 af[2][2], bf0[3][2], bf1[3][2];

#define MFMA12(AH, BH, BF)                                                     \
    _Pragma("unroll")                                                          \
    for (int mi = 0; mi < 2; ++mi)                                             \
      _Pragma("unroll")                                                        \
      for (int ni = 0; ni < 3; ++ni) {                                         \
        acc[AH][BH][mi][ni] = __builtin_amdgcn_mfma_f32_16x16x32_bf16(         \
            af[mi][0], BF[ni][0], acc[AH][BH][mi][ni], 0, 0, 0);               \
        acc[AH][BH][mi][ni] = __builtin_amdgcn_mfma_f32_16x16x32_bf16(         \
            af[mi][1], BF[ni][1], acc[AH][BH][mi][ni], 0, 0, 0);               \
      }

// P0: quadrant (A0,B0). reads af(h0)+bf0; stage next A0; vmcnt(WN).
#define PHASE0(RB, WB, KST, DO_STAGE, WN)                                      \
  {                                                                            \
    asm volatile("s_waitcnt vmcnt(" #WN ")" ::: "memory");                     \
    __builtin_amdgcn_s_barrier();                                              \
    __builtin_amdgcn_sched_barrier(0);                                         \
    _Pragma("unroll")                                                          \
    for (int mi = 0; mi < 2; ++mi)                                             \
      _Pragma("unroll")                                                        \
      for (int ks = 0; ks < 2; ++ks) af[mi][ks] = readA(RB, 0, mi, ks);        \
    _Pragma("unroll")                                                          \
    for (int ni = 0; ni < 3; ++ni)                                             \
      _Pragma("unroll")                                                        \
      for (int ks = 0; ks < 2; ++ks) bf0[ni][ks] = readB(RB, 0, ni, ks);       \
    __builtin_amdgcn_sched_barrier(0);                                         \
    if (DO_STAGE) STAGE_A(0, KST, WB);                                         \
    asm volatile("s_waitcnt lgkmcnt(0)" ::: "memory");                         \
    __builtin_amdgcn_sched_barrier(0);                                         \
    __builtin_amdgcn_s_setprio(1);                                             \
    MFMA12(0, 0, bf0)                                                          \
    __builtin_amdgcn_s_setprio(0);                                             \
  }

// P1: quadrant (A0,B1). af reused; read bf1; stage B0.
#define PHASE1(RB, WB, KST, DO_STAGE, WN)                                      \
  {                                                                            \
    asm volatile("s_waitcnt vmcnt(" #WN ")" ::: "memory");                     \
    __builtin_amdgcn_s_barrier();                                              \
    __builtin_amdgcn_sched_barrier(0);                                         \
    _Pragma("unroll")                                                          \
    for (int ni = 0; ni < 3; ++ni)                                             \
      _Pragma("unroll")                                                        \
      for (int ks = 0; ks < 2; ++ks) bf1[ni][ks] = readB(RB, 1, ni, ks);       \
    __builtin_amdgcn_sched_barrier(0);                                         \
    if (DO_STAGE) STAGE_B(0, KST, WB);                                         \
    asm volatile("s_waitcnt lgkmcnt(0)" ::: "memory");                         \
    __builtin_amdgcn_sched_barrier(0);                                         \
    __builtin_amdgcn_s_setprio(1);                                             \
    MFMA12(0, 1, bf1)                                                          \
    __builtin_amdgcn_s_setprio(0);                                             \
  }

// P2: quadrant (A1,B1). re-read af (half 1); bf1 reused; stage B1.
#define PHASE2(RB, WB, KST, DO_STAGE, WN)                                      \
  {                                                                            \
    asm volatile("s_waitcnt vmcnt(" #WN ")" ::: "memory");                     \
    __builtin_amdgcn_s_barrier();                                              \
    __builtin_amdgcn_sched_barrier(0);                                         \
    _Pragma("unroll")                                                          \
    for (int mi = 0; mi < 2; ++mi)                                             \
      _Pragma("unroll")                                                        \
      for (int ks = 0; ks < 2; ++ks) af[mi][ks] = readA(RB, 1, mi, ks);        \
    __builtin_amdgcn_sched_barrier(0);                                         \
    if (DO_STAGE) STAGE_B(1, KST, WB);                                         \
    asm volatile("s_waitcnt lgkmcnt(0)" ::: "memory");                         \
    __builtin_amdgcn_sched_barrier(0);                                         \
    __builtin_amdgcn_s_setprio(1);                                             \
    MFMA12(1, 1, bf1)                                                          \
    __builtin_amdgcn_s_setprio(0);                                             \
  }

// P3: quadrant (A1,B0). registers live; no reads/wait/barrier; stage A1.
#define PHASE3(RB, WB, KST, DO_STAGE)                                          \
  {                                                                            \
    if (DO_STAGE) STAGE_A(1, KST, WB);                                         \
    __builtin_amdgcn_s_setprio(1);                                             \
    MFMA12(1, 0, bf0)                                                          \
    __builtin_amdgcn_s_setprio(0);                                             \
  }

#define KTILE(RB, WB, KST, DO_STAGE)                                           \
  PHASE0(RB, WB, KST, DO_STAGE, 4)                                             \
  PHASE1(RB, WB, KST, DO_STAGE, 4)                                             \
  PHASE2(RB, WB, KST, DO_STAGE, 4)                                             \
  PHASE3(RB, WB, KST, DO_STAGE)

  // prologue: stage tile 0's halves in stream order (8 loads outstanding)
  STAGE_A(0, 0, 0) STAGE_B(0, 0, 0) STAGE_B(1, 0, 0) STAGE_A(1, 0, 0)

  // tiles 0..13 (pairs keep buffer indices literal); KST = (tile+1)*64
  for (int tp = 0; tp < 7; ++tp) {
    const int kb = tp * 128;
    KTILE(0, 1, kb + 64, 1)
    KTILE(1, 0, kb + 128, 1)
  }
  // tile 14: stages tile 15 into buf 1
  KTILE(0, 1, 960, 1)
  // tile 15: tail — no staging; waits 4/2/0/none
  PHASE0(1, 0, 0, 0, 4)
  PHASE1(1, 0, 0, 0, 2)
  PHASE2(1, 0, 0, 0, 0)
  PHASE3(1, 0, 0, 0)
#undef KTILE
#undef PHASE0
#undef PHASE1
#undef PHASE2
#undef PHASE3
#undef MFMA12
#undef STAGE_A
#undef STAGE_B

  // epilogue: C/D layout col = lane&15, row = (lane>>4)*4 + reg  [m89/m91]
  const int rowb = kg * 4;
#pragma unroll
  for (int ah = 0; ah < 2; ++ah)
#pragma unroll
    for (int bh = 0; bh < 2; ++bh)
#pragma unroll
      for (int ni = 0; ni < 3; ++ni) {
        const int col = n0g + bh * 96 + wn * 48 + ni * 16 + l15;
        const int cz = col & 1023;  // per-lane q/k/v select (192-tiles cross)
        const float bv_ =
            (col < 1024) ? bq[cz] : ((col < 2048) ? bk[cz] : bv[cz]);
#pragma unroll
        for (int mi = 0; mi < 2; ++mi) {
          const int row = m0 + ah * 128 + wm * 32 + mi * 16 + rowb;
#pragma unroll
          for (int j = 0; j < 4; ++j)
            QKV[(size_t)(row + j) * 3072 + col] =
                (bf16)(acc[ah][bh][mi][ni][j] + bv_);
        }
      }
}

// ------- local attention, window +-2; 2 positions per wave ----------------
__global__ void local_attn_kernel(const bf16* __restrict__ QKV,
                                  float* __restrict__ out) {
  const int t = threadIdx.x;
  const int lane = t & 63, wid = t >> 6;
  const int p0 = blockIdx.x * 8 + wid * 2;  // even
  const int s0 = p0 & 2047;
  const size_t hoff = (size_t)lane * 16;

  float q0f[16], q1f[16];
  {
    const bf16* qp = QKV + (size_t)p0 * 3072 + hoff;
    bf16x8 a0 = *reinterpret_cast<const bf16x8*>(qp);
    bf16x8 a1 = *reinterpret_cast<const bf16x8*>(qp + 8);
    bf16x8 b0 = *reinterpret_cast<const bf16x8*>(qp + 3072);
    bf16x8 b1 = *reinterpret_cast<const bf16x8*>(qp + 3072 + 8);
#pragma unroll
    for (int j = 0; j < 8; ++j) {
      q0f[j] = (float)a0[j]; q0f[8 + j] = (float)a1[j];
      q1f[j] = (float)b0[j]; q1f[8 + j] = (float)b1[j];
    }
  }

  bf16x8 kr[6][2], vr[6][2];
  bool val[6];
#pragma unroll
  for (int r = 0; r < 6; ++r) {
    const int sr = s0 - 2 + r;
    val[r] = (sr >= 0) && (sr < 2048);
    if (val[r]) {
      const bf16* kp = QKV + (size_t)(p0 - 2 + r) * 3072 + 1024 + hoff;
      kr[r][0] = *reinterpret_cast<const bf16x8*>(kp);
      kr[r][1] = *reinterpret_cast<const bf16x8*>(kp + 8);
      vr[r][0] = *reinterpret_cast<const bf16x8*>(kp + 1024);
      vr[r][1] = *reinterpret_cast<const bf16x8*>(kp + 1024 + 8);
    } else {
      bf16x8 zz;
#pragma unroll
      for (int j = 0; j < 8; ++j) zz[j] = (bf16)0.f;
      kr[r][0] = zz; kr[r][1] = zz; vr[r][0] = zz; vr[r][1] = zz;
    }
  }

  float d0[5], d1[5];
#pragma unroll
  for (int w = 0; w < 5; ++w) {
    float a = 0.f, b = 0.f;
#pragma unroll
    for (int j = 0; j < 8; ++j) {
      a += q0f[j] * (float)kr[w][0][j] + q0f[8 + j] * (float)kr[w][1][j];
      b += q1f[j] * (float)kr[w + 1][0][j] + q1f[8 + j] * (float)kr[w + 1][1][j];
    }
    d0[w] = a; d1[w] = b;
  }
#pragma unroll
  for (int off = 32; off >= 1; off >>= 1) {
#pragma unroll
    for (int w = 0; w < 5; ++w) {
      d0[w] += __shfl_xor(d0[w], off, 64);
      d1[w] += __shfl_xor(d1[w], off, 64);
    }
  }

  const float NEG = -__builtin_inff();
  float sc0[5], sc1[5];
#pragma unroll
  for (int w = 0; w < 5; ++w) {
    sc0[w] = val[w] ? d0[w] * (1.0f / 32.0f) : NEG;
    sc1[w] = val[w + 1] ? d1[w] * (1.0f / 32.0f) : NEG;
  }
  float m0_ = NEG, m1_ = NEG;
#pragma unroll
  for (int w = 0; w < 5; ++w) { m0_ = fmaxf(m0_, sc0[w]); m1_ = fmaxf(m1_, sc1[w]); }
  float e0[5], e1[5], su0 = 0.f, su1 = 0.f;
#pragma unroll
  for (int w = 0; w < 5; ++w) {
    e0[w] = __expf(sc0[w] - m0_); su0 += e0[w];
    e1[w] = __expf(sc1[w] - m1_); su1 += e1[w];
  }
  const float i0 = 1.0f / su0, i1 = 1.0f / su1;

  float of0[16], of1[16];
#pragma unroll
  for (int j = 0; j < 16; ++j) { of0[j] = 0.f; of1[j] = 0.f; }
#pragma unroll
  for (int w = 0; w < 5; ++w) {
    const float p0w = e0[w] * i0;
    const float p1w = e1[w] * i1;
#pragma unroll
    for (int j = 0; j < 8; ++j) {
      of0[j]     += p0w * (float)vr[w][0][j];
      of0[8 + j] += p0w * (float)vr[w][1][j];
      of1[j]     += p1w * (float)vr[w + 1][0][j];
      of1[8 + j] += p1w * (float)vr[w + 1][1][j];
    }
  }

  float* op0 = out + (size_t)p0 * 1024 + hoff;
  float* op1 = op0 + 1024;
#pragma unroll
  for (int j4 = 0; j4 < 4; ++j4) {
    f32x4 o0 = {of0[4 * j4], of0[4 * j4 + 1], of0[4 * j4 + 2], of0[4 * j4 + 3]};
    f32x4 o1 = {of1[4 * j4], of1[4 * j4 + 1], of1[4 * j4 + 2], of1[4 * j4 + 3]};
    *reinterpret_cast<f32x4*>(op0 + 4 * j4) = o0;
    *reinterpret_cast<f32x4*>(op1 + 4 * j4) = o1;
  }
}

extern "C" void kernel_launch(void* const* d_in, const int* in_sizes, int n_in,
                              void* d_out, int out_size, void* d_ws,
                              size_t ws_size, hipStream_t stream) {
  const float* x  = (const float*)d_in[0];
  const float* Wq = (const float*)d_in[1];
  const float* bq = (const float*)d_in[2];
  const float* Wk = (const float*)d_in[3];
  const float* bk = (const float*)d_in[4];
  const float* Wv = (const float*)d_in[5];
  const float* bv = (const float*)d_in[6];

  char* ws = (char*)d_ws;
  bf16* xb  = (bf16*)ws;                       // 16 MB: x as bf16
  bf16* Wt  = (bf16*)(ws + (size_t)16777216);  // 6 MB: [3072][1024] W^T bf16
  bf16* QKV = (bf16*)(ws + (size_t)23068672);  // 48 MB: fused [8192][3072]
  float* outf = (float*)d_out;

  prep_kernel<<<dim3(32, 32, 4), 256, 0, stream>>>(x, Wq, Wk, Wv, xb, Wt);
  qkv_gemm_kernel<<<dim3(16, 32), 512, 0, stream>>>(xb, Wt, bq, bk, bv, QKV);
  local_attn_kernel<<<1024, 256, 0, stream>>>(QKV, outf);
}